// Round 13
// baseline (1619.901 us; speedup 1.0000x reference)
//
#include <hip/hip_runtime.h>

#define D 16
#define NCH 128       // n-chunks: base=24, rem=53 -> cnt in {24,25}
#define FT 25         // FIXED trip count (pad tile contributes exactly 0)
#define TILES_MAX 25  // +1 pad slot in arrays
#define FIN_QPB 64    // queries per fin block (x 4 segments of 32 chunks)

#define LOG2E 1.4426950408889634f
#define LN2   0.6931471805599453f

// k-half plane stride in shorts: (TILES_MAX+1) tiles * 32 pts * 8 shorts
#define PLANE ((TILES_MAX + 1) * 32 * 8)

typedef __attribute__((ext_vector_type(8)))  short bf16x8;
typedef __attribute__((ext_vector_type(16))) float f32x16;

__device__ __forceinline__ unsigned short f2bf(float f) {
    unsigned u = __float_as_uint(f);
    unsigned r = (u + 0x7fffu + ((u >> 16) & 1u)) >> 16;
    return (unsigned short)r;
}

// R19: full compile-time unroll. R5/R7/R8/R10/R12 falsified per-element,
// occupancy, MFMA-latency, and iteration-count theories; the residual is the
// per-iteration machinery itself (sh_p read + lgkm wait + rotation + loop ctl)
// serialized in the ds_read->MFMA shadow. Fix: fixed 25-tile trip (zero pad
// tile contributes p=0*exp2(0)=0, replay-deterministic per R17), p preloaded
// into 25 statically-indexed VGPRs, straight-line 25x{ds_read;MFMA;16 exp/fmac}
// so the compiler pipelines ds_reads across the whole body. No loop control.
// part[chunk][q] = sum_{n in chunk} p_n * exp2( L*(x_q.d_n) ),
// p_n = w_n * 2^(-0.5*L*|d_n|^2) precomputed in staging (R13 fold).
__global__ __launch_bounds__(256, 4) void dens_kernel(
        const float* __restrict__ X, const float* __restrict__ data,
        const float* __restrict__ w, float* __restrict__ part,
        float* __restrict__ wpart, int Q, int N) {
    // two k-half planes so the B-fragment is one ds_read_b128 per tile
    __shared__ unsigned short sh_hi[2 * PLANE];            // 26.6 KB
    __shared__ float          sh_p[(TILES_MAX + 1) * 32];  // 3.3 KB
    __shared__ float          ls[4];

    const int lane  = threadIdx.x & 63;
    const int wave  = threadIdx.x >> 6;
    const int col32 = lane & 31;       // B col / D col: n-index within tile
    const int khalf = lane >> 5;       // k-half (0: k0-7, 1: k8-15)

    const int qg = blockIdx.x * 4 + wave;   // q-tile of 32 queries per wave

    // ---- this block's n-tile range (tiles of 32 points)
    const int NT = N >> 5;                       // 3125
    const int base = NT / NCH, rem = NT % NCH;
    const int chunk = blockIdx.y;
    const int tile0 = chunk * base + min(chunk, rem);
    const int cnt = base + (chunk < rem ? 1 : 0);
    const int npts = cnt * 32;
    const int n0 = tile0 * 32;

    // ---- stage: fp32 -> bf16 pack into two k-half planes + per-point weight
    float ws = 0.f;
    for (int p = threadIdx.x; p < npts; p += 256) {
        const float4* dp = (const float4*)(data + (size_t)(n0 + p) * D);
        float4 v0 = dp[0], v1 = dp[1], v2 = dp[2], v3 = dp[3];
        float vv[16] = {v0.x, v0.y, v0.z, v0.w, v1.x, v1.y, v1.z, v1.w,
                        v2.x, v2.y, v2.z, v2.w, v3.x, v3.y, v3.z, v3.w};
        float dd = 0.f;
        unsigned hp[8];
        #pragma unroll
        for (int j = 0; j < 8; j++) {
            float a = vv[2 * j], b = vv[2 * j + 1];
            dd = fmaf(a, a, fmaf(b, b, dd));
            hp[j] = (unsigned)f2bf(a) | ((unsigned)f2bf(b) << 16);
        }
        *(uint4*)(sh_hi + p * 8)         = make_uint4(hp[0], hp[1], hp[2], hp[3]);
        *(uint4*)(sh_hi + PLANE + p * 8) = make_uint4(hp[4], hp[5], hp[6], hp[7]);
        float wn = w[n0 + p];
        ws += wn;
        sh_p[p] = wn * __builtin_amdgcn_exp2f(-0.5f * LOG2E * dd);
    }
    // deterministic pad tile (tile `cnt`, consumed only by cnt==24 blocks'
    // 25th unrolled step where p=0 makes it exactly zero-contribution)
    if (threadIdx.x < 64) {
        int t = threadIdx.x;
        int half = t >> 5;
        int slot = t & 31;
        *(uint4*)(sh_hi + half * PLANE + (npts + slot) * 8) =
            make_uint4(0u, 0u, 0u, 0u);
        if (slot == t && t < 32) sh_p[npts + t] = 0.f;
    }
    #pragma unroll
    for (int off = 32; off > 0; off >>= 1) ws += __shfl_down(ws, off, 64);
    if (lane == 0) ls[wave] = ws;

    // ---- A fragment: bf16(L*x), row = col32, k = khalf*8 + j  (full K=16 used)
    bf16x8 afrag;
    {
        int q = qg * 32 + col32;
        const float* xp = X + (size_t)q * D + khalf * 8;
        #pragma unroll
        for (int j = 0; j < 8; j++)
            afrag[j] = (short)f2bf(xp[j] * LOG2E);
    }

    f32x16 dens, zc;
    #pragma unroll
    for (int r = 0; r < 16; r++) { dens[r] = 0.f; zc[r] = 0.f; }

    __syncthreads();

    if (threadIdx.x == 0)
        wpart[chunk] = (ls[0] + ls[1]) + (ls[2] + ls[3]);

    // ---- p values into registers (statically indexed via full unroll)
    float preg[FT];
    #pragma unroll
    for (int t = 0; t < FT; t++) preg[t] = sh_p[t * 32 + col32];

    // ---- straight-line main body: 25 x { ds_read_b128; MFMA; 16 exp/fmac }
    const int eoff = khalf * PLANE + col32 * 8;  // shorts
    #pragma unroll
    for (int it = 0; it < FT; it++) {
        bf16x8 b = *(const bf16x8*)(sh_hi + it * 256 + eoff);
        f32x16 s = __builtin_amdgcn_mfma_f32_32x32x16_bf16(afrag, b, zc, 0, 0, 0);
        float p0 = preg[it];
        #pragma unroll
        for (int r = 0; r < 16; r++)
            dens[r] = fmaf(p0, __builtin_amdgcn_exp2f(s[r]), dens[r]);
    }

    // ---- reduce over the 32 n-lanes (cols), plain store (no atomics)
    #pragma unroll
    for (int r = 0; r < 16; r++) {
        float v = dens[r];
        v += __shfl_xor(v, 1, 64);
        v += __shfl_xor(v, 2, 64);
        v += __shfl_xor(v, 4, 64);
        v += __shfl_xor(v, 8, 64);
        v += __shfl_xor(v, 16, 64);
        if (col32 == 0) {
            int q = qg * 32 + (r & 3) + 8 * (r >> 2) + 4 * khalf;
            part[(size_t)chunk * Q + q] = v;
        }
    }
}

// ---------------- finalize: parallel chunk reduce + wave-parallel wsum + log ------
// 32 blocks x 256 threads; each block covers 64 queries, 4 threads per query
// (each summing 32 chunks, coalesced), LDS combine, 64 threads finalize.
__global__ __launch_bounds__(256) void fin_kernel(
        const float* __restrict__ X, const float* __restrict__ part,
        const float* __restrict__ wpart, float* __restrict__ out, int Q) {
    __shared__ float sred[4][FIN_QPB];
    __shared__ float swsum;

    const int tid = threadIdx.x;
    const int qi = tid & (FIN_QPB - 1);
    const int seg = tid >> 6;              // which 32-chunk segment (0..3)
    const int q = blockIdx.x * FIN_QPB + qi;

    // partial sum over this segment's 32 chunks (coalesced across qi lanes)
    float a0 = 0.f, a1 = 0.f, a2 = 0.f, a3 = 0.f;
    const int c0 = seg * 32;
    #pragma unroll 4
    for (int c = 0; c < 32; c += 4) {
        a0 += part[(size_t)(c0 + c + 0) * Q + q];
        a1 += part[(size_t)(c0 + c + 1) * Q + q];
        a2 += part[(size_t)(c0 + c + 2) * Q + q];
        a3 += part[(size_t)(c0 + c + 3) * Q + q];
    }
    sred[seg][qi] = (a0 + a1) + (a2 + a3);

    // wave 0: wsum via 2 loads/lane + shuffle reduce (128 chunks)
    if (tid < 64) {
        float wv = wpart[tid] + wpart[tid + 64];
        #pragma unroll
        for (int off = 32; off > 0; off >>= 1) wv += __shfl_down(wv, off, 64);
        if (tid == 0) swsum = wv;
    }
    __syncthreads();

    if (tid < FIN_QPB) {
        float dsum = (sred[0][tid] + sred[1][tid]) + (sred[2][tid] + sred[3][tid]);
        int qq = blockIdx.x * FIN_QPB + tid;
        const float4* xp = (const float4*)(X + (size_t)qq * D);
        float4 x0 = xp[0], x1 = xp[1], x2 = xp[2], x3 = xp[3];
        float xx = x0.x*x0.x + x0.y*x0.y + x0.z*x0.z + x0.w*x0.w
                 + x1.x*x1.x + x1.y*x1.y + x1.z*x1.z + x1.w*x1.w
                 + x2.x*x2.x + x2.y*x2.y + x2.z*x2.z + x2.w*x2.w
                 + x3.x*x3.x + x3.y*x3.y + x3.z*x3.z + x3.w*x3.w;
        float aq = -0.5f * LOG2E * xx;
        const float ln_norm = -8.f * 1.8378770664093453f;  // ln((2*pi)^-8)
        out[qq] = LN2 * (aq + __builtin_amdgcn_logf(dsum)
                            - __builtin_amdgcn_logf(swsum)) + ln_norm;
    }
}

extern "C" void kernel_launch(void* const* d_in, const int* in_sizes, int n_in,
                              void* d_out, int out_size, void* d_ws, size_t ws_size,
                              hipStream_t stream) {
    const float* X    = (const float*)d_in[0];
    const float* data = (const float*)d_in[1];
    const float* w    = (const float*)d_in[2];
    float* out = (float*)d_out;
    int Q = in_sizes[0] / D;   // 2048
    int N = in_sizes[1] / D;   // 100000

    // ws layout (floats): [0..NCH) wpart, then part (NCH*Q floats).
    // Everything written before read each launch -> no memset needed.
    float* wpart = (float*)d_ws;
    float* part  = wpart + NCH;

    dim3 grid(Q / (4 * 32), NCH);   // (16, 128)
    dens_kernel<<<grid, 256, 0, stream>>>(X, data, w, part, wpart, Q, N);

    fin_kernel<<<Q / FIN_QPB, 256, 0, stream>>>(X, part, wpart, out, Q);
}

// Round 15
// 180.431 us; speedup vs baseline: 8.9779x; 8.9779x over previous
//
#include <hip/hip_runtime.h>

#define D 16
#define NCH 128       // n-chunks: grid (8,128)=1024 blocks, 4/CU co-residency
#define TILES_MAX 25  // ceil(3125/128) = 25 tiles of 32 points
#define LOG2E 1.4426950408889634f
#define LN2   0.6931471805599453f

// k-half plane stride in shorts: (TILES_MAX+1) tiles * 32 pts * 8 shorts
#define PLANE ((TILES_MAX + 1) * 32 * 8)

typedef __attribute__((ext_vector_type(8)))  short bf16x8;
typedef __attribute__((ext_vector_type(16))) float f32x16;

__device__ __forceinline__ unsigned short f2bf(float f) {
    unsigned u = __float_as_uint(f);
    unsigned r = (u + 0x7fffu + ((u >> 16) & 1u)) >> 16;
    return (unsigned short)r;
}

// R21: fuse fin via atomic-counter tail (cooperative launch proved unsupported
// under graph capture in R20 — kernel never ran). After part stores:
// threadfence + atomicAdd(cnt[bx]); the LAST block of each bx-slice (old==127)
// finalizes that slice's 256 queries (1 thread = 1 query, 128-chunk column sum,
// L2-resident). cnt[8] zeroed by hipMemsetAsync before launch (capture-safe).
// No dispatch-order assumption: completion counting only (G12/G16).
// dens body = R18 (WQT=2, passed) + R17 deterministic pad staging.
// part[chunk][q] = sum_{n in chunk} p_n * exp2( L*(x_q.d_n) ),
// p_n = w_n * 2^(-0.5*L*|d_n|^2) precomputed in staging (R13 fold).
__global__ __launch_bounds__(256, 4) void dens_kernel(
        const float* __restrict__ X, const float* __restrict__ data,
        const float* __restrict__ w, float* __restrict__ part,
        float* __restrict__ wpart, int* __restrict__ cnt,
        float* __restrict__ out, int Q, int N) {
    // two k-half planes so the B-fragment is one ds_read_b128 per tile
    __shared__ unsigned short sh_hi[2 * PLANE];            // 26.6 KB
    __shared__ float          sh_p[(TILES_MAX + 1) * 32];  // 3.3 KB
    __shared__ float          ls[4];
    __shared__ int            is_last;
    __shared__ float          swsum;

    const int lane  = threadIdx.x & 63;
    const int wave  = threadIdx.x >> 6;
    const int col32 = lane & 31;       // B col / D col: n-index within tile
    const int khalf = lane >> 5;       // k-half (0: k0-7, 1: k8-15)

    const int qg = blockIdx.x * 4 + wave;   // pair of q-tiles (2 x 32 queries)

    // ---- this block's n-tile range (tiles of 32 points)
    const int NT = N >> 5;                       // 3125
    const int base = NT / NCH, rem = NT % NCH;
    const int chunk = blockIdx.y;
    const int tile0 = chunk * base + min(chunk, rem);
    const int cnt_t = base + (chunk < rem ? 1 : 0);
    const int npts = cnt_t * 32;
    const int n0 = tile0 * 32;

    // ---- stage: fp32 -> bf16 pack into two k-half planes + per-point weight
    float ws = 0.f;
    for (int p = threadIdx.x; p < npts; p += 256) {
        const float4* dp = (const float4*)(data + (size_t)(n0 + p) * D);
        float4 v0 = dp[0], v1 = dp[1], v2 = dp[2], v3 = dp[3];
        float vv[16] = {v0.x, v0.y, v0.z, v0.w, v1.x, v1.y, v1.z, v1.w,
                        v2.x, v2.y, v2.z, v2.w, v3.x, v3.y, v3.z, v3.w};
        float dd = 0.f;
        unsigned hp[8];
        #pragma unroll
        for (int j = 0; j < 8; j++) {
            float a = vv[2 * j], b = vv[2 * j + 1];
            dd = fmaf(a, a, fmaf(b, b, dd));
            hp[j] = (unsigned)f2bf(a) | ((unsigned)f2bf(b) << 16);
        }
        *(uint4*)(sh_hi + p * 8)         = make_uint4(hp[0], hp[1], hp[2], hp[3]);
        *(uint4*)(sh_hi + PLANE + p * 8) = make_uint4(hp[4], hp[5], hp[6], hp[7]);
        float wn = w[n0 + p];
        ws += wn;
        sh_p[p] = wn * __builtin_amdgcn_exp2f(-0.5f * LOG2E * dd);
    }
    // deterministic pad tile (read by the depth-1 prefetch, never consumed)
    if (threadIdx.x < 64) {
        int t = threadIdx.x;
        int half = t >> 5;
        int slot = t & 31;
        *(uint4*)(sh_hi + half * PLANE + (npts + slot) * 8) =
            make_uint4(0u, 0u, 0u, 0u);
        if (slot == t && t < 32) sh_p[npts + t] = 0.f;
    }
    #pragma unroll
    for (int off = 32; off > 0; off >>= 1) ws += __shfl_down(ws, off, 64);
    if (lane == 0) ls[wave] = ws;

    // ---- A fragments (2 q-tiles): bf16(L*x), row = col32, k = khalf*8 + j
    bf16x8 afrag0, afrag1;
    {
        int q0 = (qg * 2 + 0) * 32 + col32;
        int q1 = (qg * 2 + 1) * 32 + col32;
        const float* xp0 = X + (size_t)q0 * D + khalf * 8;
        const float* xp1 = X + (size_t)q1 * D + khalf * 8;
        #pragma unroll
        for (int j = 0; j < 8; j++) {
            afrag0[j] = (short)f2bf(xp0[j] * LOG2E);
            afrag1[j] = (short)f2bf(xp1[j] * LOG2E);
        }
    }

    f32x16 dens0, dens1, zc;
    #pragma unroll
    for (int r = 0; r < 16; r++) { dens0[r] = 0.f; dens1[r] = 0.f; zc[r] = 0.f; }

    __syncthreads();

    if (threadIdx.x == 0)
        wpart[chunk] = (ls[0] + ls[1]) + (ls[2] + ls[3]);

    // ---- main loop: one B-read feeds 2 MFMAs -> 32 exp/fmac per iteration
    const int eoff = khalf * PLANE + col32 * 8;  // shorts
    bf16x8 b1 = *(const bf16x8*)(sh_hi + eoff);
    float  p0 = sh_p[col32];
    #pragma unroll 2
    for (int it = 0; it < cnt_t; it++) {
        bf16x8 nb1 = *(const bf16x8*)(sh_hi + (it + 1) * 256 + eoff);
        float  np0 = sh_p[(it + 1) * 32 + col32];
        f32x16 s0 = __builtin_amdgcn_mfma_f32_32x32x16_bf16(afrag0, b1, zc, 0, 0, 0);
        f32x16 s1 = __builtin_amdgcn_mfma_f32_32x32x16_bf16(afrag1, b1, zc, 0, 0, 0);
        #pragma unroll
        for (int r = 0; r < 16; r++)
            dens0[r] = fmaf(p0, __builtin_amdgcn_exp2f(s0[r]), dens0[r]);
        #pragma unroll
        for (int r = 0; r < 16; r++)
            dens1[r] = fmaf(p0, __builtin_amdgcn_exp2f(s1[r]), dens1[r]);
        b1 = nb1; p0 = np0;
    }

    // ---- reduce over the 32 n-lanes (cols), plain store (no atomics)
    #pragma unroll
    for (int t = 0; t < 2; t++) {
        #pragma unroll
        for (int r = 0; r < 16; r++) {
            float v = (t == 0) ? dens0[r] : dens1[r];
            v += __shfl_xor(v, 1, 64);
            v += __shfl_xor(v, 2, 64);
            v += __shfl_xor(v, 4, 64);
            v += __shfl_xor(v, 8, 64);
            v += __shfl_xor(v, 16, 64);
            if (col32 == 0) {
                int q = (qg * 2 + t) * 32 + (r & 3) + 8 * (r >> 2) + 4 * khalf;
                part[(size_t)chunk * Q + q] = v;
            }
        }
    }

    // ---- tail: last block of this bx-slice finalizes its 256 queries
    __threadfence();                        // publish part/wpart device-wide
    if (threadIdx.x == 0) {
        int old = atomicAdd(&cnt[blockIdx.x], 1);
        is_last = (old == (int)gridDim.y - 1);
    }
    __syncthreads();
    if (is_last) {
        __threadfence();                    // acquire other blocks' stores
        const int tid = threadIdx.x;
        if (tid < 64) {
            float wv = wpart[tid] + wpart[tid + 64];
            #pragma unroll
            for (int off = 32; off > 0; off >>= 1) wv += __shfl_down(wv, off, 64);
            if (tid == 0) swsum = wv;
        }
        __syncthreads();

        int qq = blockIdx.x * 256 + tid;    // 1 thread = 1 query
        float a0 = 0.f, a1 = 0.f, a2 = 0.f, a3 = 0.f;
        #pragma unroll 4
        for (int c = 0; c < NCH; c += 4) {
            a0 += part[(size_t)(c + 0) * Q + qq];
            a1 += part[(size_t)(c + 1) * Q + qq];
            a2 += part[(size_t)(c + 2) * Q + qq];
            a3 += part[(size_t)(c + 3) * Q + qq];
        }
        float dsum = (a0 + a1) + (a2 + a3);

        const float4* xp = (const float4*)(X + (size_t)qq * D);
        float4 x0 = xp[0], x1 = xp[1], x2 = xp[2], x3 = xp[3];
        float xx = x0.x*x0.x + x0.y*x0.y + x0.z*x0.z + x0.w*x0.w
                 + x1.x*x1.x + x1.y*x1.y + x1.z*x1.z + x1.w*x1.w
                 + x2.x*x2.x + x2.y*x2.y + x2.z*x2.z + x2.w*x2.w
                 + x3.x*x3.x + x3.y*x3.y + x3.z*x3.z + x3.w*x3.w;
        float aq = -0.5f * LOG2E * xx;
        const float ln_norm = -8.f * 1.8378770664093453f;  // ln((2*pi)^-8)
        out[qq] = LN2 * (aq + __builtin_amdgcn_logf(dsum)
                            - __builtin_amdgcn_logf(swsum)) + ln_norm;
    }
}

extern "C" void kernel_launch(void* const* d_in, const int* in_sizes, int n_in,
                              void* d_out, int out_size, void* d_ws, size_t ws_size,
                              hipStream_t stream) {
    const float* X    = (const float*)d_in[0];
    const float* data = (const float*)d_in[1];
    const float* w    = (const float*)d_in[2];
    float* out = (float*)d_out;
    int Q = in_sizes[0] / D;   // 2048
    int N = in_sizes[1] / D;   // 100000

    // ws layout (floats): [0..NCH) wpart, part (NCH*Q), then cnt[8] (ints).
    float* wpart = (float*)d_ws;
    float* part  = wpart + NCH;
    int*   cnt   = (int*)(part + (size_t)NCH * Q);

    hipMemsetAsync(cnt, 0, 8 * sizeof(int), stream);   // capture-safe node

    dim3 grid(Q / (4 * 2 * 32), NCH);   // (8, 128)
    dens_kernel<<<grid, 256, 0, stream>>>(X, data, w, part, wpart, cnt,
                                          out, Q, N);
}

// Round 16
// 101.069 us; speedup vs baseline: 16.0277x; 1.7852x over previous
//
#include <hip/hip_runtime.h>

#define D 16
#define NCH 128       // n-chunks: grid (8,128)=1024 blocks, 4/CU co-residency
#define TILES_MAX 25  // ceil(3125/128) = 25 tiles of 32 points
#define LOG2E 1.4426950408889634f
#define LN2   0.6931471805599453f

// k-half plane stride in shorts: (TILES_MAX+1) tiles * 32 pts * 8 shorts
#define PLANE ((TILES_MAX + 1) * 32 * 8)

typedef __attribute__((ext_vector_type(8)))  short bf16x8;
typedef __attribute__((ext_vector_type(16))) float f32x16;

__device__ __forceinline__ unsigned short f2bf(float f) {
    unsigned u = __float_as_uint(f);
    unsigned r = (u + 0x7fffu + ((u >> 16) & 1u)) >> 16;
    return (unsigned short)r;
}

// R22: fence-FREE fused tail. R15 diagnosed: __threadfence() per block emits
// an L2-writeback cache-op; 1024 resident blocks' writebacks serialize ->
// +85us stall. Replacement: per-access coherent ops (no cache-ops at all):
//   - part/wpart written via __hip_atomic_store(AGENT) (write-through),
//   - per-wave s_waitcnt vmcnt(0) + syncthreads before ONE relaxed AGENT
//     atomic_fetch_add on cnt[bx] (when last sees 127, all stores are at the
//     coherent point - each block drained vmcnt before incrementing),
//   - last block reads part via __hip_atomic_load(AGENT) (bypasses stale
//     local caches), 8-deep ILP, finalizes its 256 queries.
// Hot loop = R18 body (WQT=2, (256,4)) + R17 deterministic pad staging.
// part[chunk][q] = sum_{n in chunk} p_n * exp2( L*(x_q.d_n) ),
// p_n = w_n * 2^(-0.5*L*|d_n|^2) precomputed in staging (R13 fold).
__global__ __launch_bounds__(256, 4) void dens_kernel(
        const float* __restrict__ X, const float* __restrict__ data,
        const float* __restrict__ w, float* __restrict__ part,
        float* __restrict__ wpart, int* __restrict__ cnt,
        float* __restrict__ out, int Q, int N) {
    // two k-half planes so the B-fragment is one ds_read_b128 per tile
    __shared__ unsigned short sh_hi[2 * PLANE];            // 26.6 KB
    __shared__ float          sh_p[(TILES_MAX + 1) * 32];  // 3.3 KB
    __shared__ float          ls[4];
    __shared__ int            is_last;
    __shared__ float          swsum;

    const int lane  = threadIdx.x & 63;
    const int wave  = threadIdx.x >> 6;
    const int col32 = lane & 31;       // B col / D col: n-index within tile
    const int khalf = lane >> 5;       // k-half (0: k0-7, 1: k8-15)

    const int qg = blockIdx.x * 4 + wave;   // pair of q-tiles (2 x 32 queries)

    // ---- this block's n-tile range (tiles of 32 points)
    const int NT = N >> 5;                       // 3125
    const int base = NT / NCH, rem = NT % NCH;
    const int chunk = blockIdx.y;
    const int tile0 = chunk * base + min(chunk, rem);
    const int cnt_t = base + (chunk < rem ? 1 : 0);
    const int npts = cnt_t * 32;
    const int n0 = tile0 * 32;

    // ---- stage: fp32 -> bf16 pack into two k-half planes + per-point weight
    float ws = 0.f;
    for (int p = threadIdx.x; p < npts; p += 256) {
        const float4* dp = (const float4*)(data + (size_t)(n0 + p) * D);
        float4 v0 = dp[0], v1 = dp[1], v2 = dp[2], v3 = dp[3];
        float vv[16] = {v0.x, v0.y, v0.z, v0.w, v1.x, v1.y, v1.z, v1.w,
                        v2.x, v2.y, v2.z, v2.w, v3.x, v3.y, v3.z, v3.w};
        float dd = 0.f;
        unsigned hp[8];
        #pragma unroll
        for (int j = 0; j < 8; j++) {
            float a = vv[2 * j], b = vv[2 * j + 1];
            dd = fmaf(a, a, fmaf(b, b, dd));
            hp[j] = (unsigned)f2bf(a) | ((unsigned)f2bf(b) << 16);
        }
        *(uint4*)(sh_hi + p * 8)         = make_uint4(hp[0], hp[1], hp[2], hp[3]);
        *(uint4*)(sh_hi + PLANE + p * 8) = make_uint4(hp[4], hp[5], hp[6], hp[7]);
        float wn = w[n0 + p];
        ws += wn;
        sh_p[p] = wn * __builtin_amdgcn_exp2f(-0.5f * LOG2E * dd);
    }
    // deterministic pad tile (read by the depth-1 prefetch, never consumed)
    if (threadIdx.x < 64) {
        int t = threadIdx.x;
        int half = t >> 5;
        int slot = t & 31;
        *(uint4*)(sh_hi + half * PLANE + (npts + slot) * 8) =
            make_uint4(0u, 0u, 0u, 0u);
        if (slot == t && t < 32) sh_p[npts + t] = 0.f;
    }
    #pragma unroll
    for (int off = 32; off > 0; off >>= 1) ws += __shfl_down(ws, off, 64);
    if (lane == 0) ls[wave] = ws;

    // ---- A fragments (2 q-tiles): bf16(L*x), row = col32, k = khalf*8 + j
    bf16x8 afrag0, afrag1;
    {
        int q0 = (qg * 2 + 0) * 32 + col32;
        int q1 = (qg * 2 + 1) * 32 + col32;
        const float* xp0 = X + (size_t)q0 * D + khalf * 8;
        const float* xp1 = X + (size_t)q1 * D + khalf * 8;
        #pragma unroll
        for (int j = 0; j < 8; j++) {
            afrag0[j] = (short)f2bf(xp0[j] * LOG2E);
            afrag1[j] = (short)f2bf(xp1[j] * LOG2E);
        }
    }

    f32x16 dens0, dens1, zc;
    #pragma unroll
    for (int r = 0; r < 16; r++) { dens0[r] = 0.f; dens1[r] = 0.f; zc[r] = 0.f; }

    __syncthreads();

    if (threadIdx.x == 0)
        __hip_atomic_store(&wpart[chunk], (ls[0] + ls[1]) + (ls[2] + ls[3]),
                           __ATOMIC_RELAXED, __HIP_MEMORY_SCOPE_AGENT);

    // ---- main loop: one B-read feeds 2 MFMAs -> 32 exp/fmac per iteration
    const int eoff = khalf * PLANE + col32 * 8;  // shorts
    bf16x8 b1 = *(const bf16x8*)(sh_hi + eoff);
    float  p0 = sh_p[col32];
    #pragma unroll 2
    for (int it = 0; it < cnt_t; it++) {
        bf16x8 nb1 = *(const bf16x8*)(sh_hi + (it + 1) * 256 + eoff);
        float  np0 = sh_p[(it + 1) * 32 + col32];
        f32x16 s0 = __builtin_amdgcn_mfma_f32_32x32x16_bf16(afrag0, b1, zc, 0, 0, 0);
        f32x16 s1 = __builtin_amdgcn_mfma_f32_32x32x16_bf16(afrag1, b1, zc, 0, 0, 0);
        #pragma unroll
        for (int r = 0; r < 16; r++)
            dens0[r] = fmaf(p0, __builtin_amdgcn_exp2f(s0[r]), dens0[r]);
        #pragma unroll
        for (int r = 0; r < 16; r++)
            dens1[r] = fmaf(p0, __builtin_amdgcn_exp2f(s1[r]), dens1[r]);
        b1 = nb1; p0 = np0;
    }

    // ---- reduce over the 32 n-lanes (cols), agent-coherent scalar stores
    #pragma unroll
    for (int t = 0; t < 2; t++) {
        #pragma unroll
        for (int r = 0; r < 16; r++) {
            float v = (t == 0) ? dens0[r] : dens1[r];
            v += __shfl_xor(v, 1, 64);
            v += __shfl_xor(v, 2, 64);
            v += __shfl_xor(v, 4, 64);
            v += __shfl_xor(v, 8, 64);
            v += __shfl_xor(v, 16, 64);
            if (col32 == 0) {
                int q = (qg * 2 + t) * 32 + (r & 3) + 8 * (r >> 2) + 4 * khalf;
                __hip_atomic_store(&part[(size_t)chunk * Q + q], v,
                                   __ATOMIC_RELAXED, __HIP_MEMORY_SCOPE_AGENT);
            }
        }
    }

    // ---- completion handshake: drain this wave's stores, then count
    asm volatile("s_waitcnt vmcnt(0)" ::: "memory");
    __syncthreads();     // all waves' stores are at the coherent point
    if (threadIdx.x == 0) {
        int old = __hip_atomic_fetch_add(&cnt[blockIdx.x], 1,
                                         __ATOMIC_RELAXED,
                                         __HIP_MEMORY_SCOPE_AGENT);
        is_last = (old == (int)gridDim.y - 1);
    }
    __syncthreads();

    // ---- tail: last block of this bx-slice finalizes its 256 queries
    if (is_last) {
        const int tid = threadIdx.x;
        if (tid < 64) {
            float wv = __hip_atomic_load(&wpart[tid], __ATOMIC_RELAXED,
                                         __HIP_MEMORY_SCOPE_AGENT)
                     + __hip_atomic_load(&wpart[tid + 64], __ATOMIC_RELAXED,
                                         __HIP_MEMORY_SCOPE_AGENT);
            #pragma unroll
            for (int off = 32; off > 0; off >>= 1) wv += __shfl_down(wv, off, 64);
            if (tid == 0) swsum = wv;
        }
        __syncthreads();

        int qq = blockIdx.x * 256 + tid;    // 1 thread = 1 query
        float a[8];
        #pragma unroll
        for (int j = 0; j < 8; j++) a[j] = 0.f;
        #pragma unroll 2
        for (int c = 0; c < NCH; c += 8) {
            #pragma unroll
            for (int j = 0; j < 8; j++)
                a[j] += __hip_atomic_load(&part[(size_t)(c + j) * Q + qq],
                                          __ATOMIC_RELAXED,
                                          __HIP_MEMORY_SCOPE_AGENT);
        }
        float dsum = ((a[0] + a[1]) + (a[2] + a[3]))
                   + ((a[4] + a[5]) + (a[6] + a[7]));

        const float4* xp = (const float4*)(X + (size_t)qq * D);
        float4 x0 = xp[0], x1 = xp[1], x2 = xp[2], x3 = xp[3];
        float xx = x0.x*x0.x + x0.y*x0.y + x0.z*x0.z + x0.w*x0.w
                 + x1.x*x1.x + x1.y*x1.y + x1.z*x1.z + x1.w*x1.w
                 + x2.x*x2.x + x2.y*x2.y + x2.z*x2.z + x2.w*x2.w
                 + x3.x*x3.x + x3.y*x3.y + x3.z*x3.z + x3.w*x3.w;
        float aq = -0.5f * LOG2E * xx;
        const float ln_norm = -8.f * 1.8378770664093453f;  // ln((2*pi)^-8)
        out[qq] = LN2 * (aq + __builtin_amdgcn_logf(dsum)
                            - __builtin_amdgcn_logf(swsum)) + ln_norm;
    }
}

extern "C" void kernel_launch(void* const* d_in, const int* in_sizes, int n_in,
                              void* d_out, int out_size, void* d_ws, size_t ws_size,
                              hipStream_t stream) {
    const float* X    = (const float*)d_in[0];
    const float* data = (const float*)d_in[1];
    const float* w    = (const float*)d_in[2];
    float* out = (float*)d_out;
    int Q = in_sizes[0] / D;   // 2048
    int N = in_sizes[1] / D;   // 100000

    // ws layout (floats): [0..NCH) wpart, part (NCH*Q), then cnt[8] (ints).
    float* wpart = (float*)d_ws;
    float* part  = wpart + NCH;
    int*   cnt   = (int*)(part + (size_t)NCH * Q);

    hipMemsetAsync(cnt, 0, 8 * sizeof(int), stream);   // capture-safe node

    dim3 grid(Q / (4 * 2 * 32), NCH);   // (8, 128)
    dens_kernel<<<grid, 256, 0, stream>>>(X, data, w, part, wpart, cnt,
                                          out, Q, N);
}

// Round 17
// 92.880 us; speedup vs baseline: 17.4408x; 1.0882x over previous
//
#include <hip/hip_runtime.h>

#define D 16
#define NCH 128       // n-chunks: grid (16,128)=2048 blocks = 2 even rounds of
                      // 4 blocks/CU (launch_bounds(256,4) regime)
#define TILES_MAX 25  // ceil(3125/128) = 25 tiles of 32 points
#define FIN_QPB 64    // queries per fin block (x 4 segments of 32 chunks)

#define LOG2E 1.4426950408889634f
#define LN2   0.6931471805599453f

// k-half plane stride in shorts: (TILES_MAX+1) tiles * 32 pts * 8 shorts
#define PLANE ((TILES_MAX + 1) * 32 * 8)

typedef __attribute__((ext_vector_type(8)))  short bf16x8;
typedef __attribute__((ext_vector_type(16))) float f32x16;

__device__ __forceinline__ unsigned short f2bf(float f) {
    unsigned u = __float_as_uint(f);
    unsigned r = (u + 0x7fffu + ((u >> 16) & 1u)) >> 16;
    return (unsigned short)r;
}

// R23: restore R11 exactly (best verified: 91.96us, passed, replay-stable).
// R14/R15/R16 closed the fusion family: cooperative launch doesn't run under
// graph capture; per-block __threadfence serializes 1024 L2 writebacks (+85us);
// coherent-tail adds +9us stall to dens and the "gap" it targets is mostly
// fixed replay overhead. dens (~36.5us) is invariant (+-1us) under 9 structural
// levers (R5-R13); its VALU-busy floor is ~17us. Total budget: fill 40.5
// (uncontrollable) + dens 36.5 + fin ~4 + fixed overhead ~11.
// part[chunk][q] = sum_{n in chunk} p_n * exp2( L*(x_q.d_n) ),
// p_n = w_n * 2^(-0.5*L*|d_n|^2) precomputed in staging (R13 fold).
__global__ __launch_bounds__(256, 4) void dens_kernel(
        const float* __restrict__ X, const float* __restrict__ data,
        const float* __restrict__ w, float* __restrict__ part,
        float* __restrict__ wpart, int Q, int N) {
    // two k-half planes so the B-fragment is one ds_read_b128 per tile
    __shared__ unsigned short sh_hi[2 * PLANE];            // 26.6 KB
    __shared__ float          sh_p[(TILES_MAX + 1) * 32];  // 3.3 KB
    __shared__ float          ls[4];

    const int lane  = threadIdx.x & 63;
    const int wave  = threadIdx.x >> 6;
    const int col32 = lane & 31;       // B col / D col: n-index within tile
    const int khalf = lane >> 5;       // k-half (0: k0-7, 1: k8-15)

    const int qg = blockIdx.x * 4 + wave;   // q-tile of 32 queries per wave

    // ---- this block's n-tile range (tiles of 32 points)
    const int NT = N >> 5;                       // 3125
    const int base = NT / NCH, rem = NT % NCH;
    const int chunk = blockIdx.y;
    const int tile0 = chunk * base + min(chunk, rem);
    const int cnt = base + (chunk < rem ? 1 : 0);
    const int npts = cnt * 32;
    const int n0 = tile0 * 32;

    // ---- stage: fp32 -> bf16 pack into two k-half planes + per-point weight
    float ws = 0.f;
    for (int p = threadIdx.x; p < npts; p += 256) {
        const float4* dp = (const float4*)(data + (size_t)(n0 + p) * D);
        float4 v0 = dp[0], v1 = dp[1], v2 = dp[2], v3 = dp[3];
        float vv[16] = {v0.x, v0.y, v0.z, v0.w, v1.x, v1.y, v1.z, v1.w,
                        v2.x, v2.y, v2.z, v2.w, v3.x, v3.y, v3.z, v3.w};
        float dd = 0.f;
        unsigned hp[8];
        #pragma unroll
        for (int j = 0; j < 8; j++) {
            float a = vv[2 * j], b = vv[2 * j + 1];
            dd = fmaf(a, a, fmaf(b, b, dd));
            hp[j] = (unsigned)f2bf(a) | ((unsigned)f2bf(b) << 16);
        }
        *(uint4*)(sh_hi + p * 8)         = make_uint4(hp[0], hp[1], hp[2], hp[3]);
        *(uint4*)(sh_hi + PLANE + p * 8) = make_uint4(hp[4], hp[5], hp[6], hp[7]);
        float wn = w[n0 + p];
        ws += wn;
        sh_p[p] = wn * __builtin_amdgcn_exp2f(-0.5f * LOG2E * dd);
    }
    // deterministic pad tile (read by the depth-1 prefetch, never consumed):
    // 64 threads zero both k-half planes of tile `cnt`; 32 threads zero sh_p pad.
    if (threadIdx.x < 64) {
        int t = threadIdx.x;
        int half = t >> 5;
        int slot = t & 31;
        *(uint4*)(sh_hi + half * PLANE + (npts + slot) * 8) =
            make_uint4(0u, 0u, 0u, 0u);
        if (slot == t && t < 32) sh_p[npts + t] = 0.f;
    }
    #pragma unroll
    for (int off = 32; off > 0; off >>= 1) ws += __shfl_down(ws, off, 64);
    if (lane == 0) ls[wave] = ws;

    // ---- A fragment: bf16(L*x), row = col32, k = khalf*8 + j  (full K=16 used)
    bf16x8 afrag;
    {
        int q = qg * 32 + col32;
        const float* xp = X + (size_t)q * D + khalf * 8;
        #pragma unroll
        for (int j = 0; j < 8; j++)
            afrag[j] = (short)f2bf(xp[j] * LOG2E);
    }

    f32x16 dens, zc;
    #pragma unroll
    for (int r = 0; r < 16; r++) { dens[r] = 0.f; zc[r] = 0.f; }

    __syncthreads();

    if (threadIdx.x == 0)
        wpart[chunk] = (ls[0] + ls[1]) + (ls[2] + ls[3]);

    // ---- main loop: depth-1 LDS prefetch; MFMA(C=zero) -> exp2 -> fmac(p0)
    const int eoff = khalf * PLANE + col32 * 8;  // shorts
    bf16x8 b1 = *(const bf16x8*)(sh_hi + eoff);
    float  p0 = sh_p[col32];
    #pragma unroll 2
    for (int it = 0; it < cnt; it++) {
        bf16x8 nb1 = *(const bf16x8*)(sh_hi + (it + 1) * 256 + eoff);
        float  np0 = sh_p[(it + 1) * 32 + col32];
        f32x16 s = __builtin_amdgcn_mfma_f32_32x32x16_bf16(afrag, b1, zc, 0, 0, 0);
        #pragma unroll
        for (int r = 0; r < 16; r++)
            dens[r] = fmaf(p0, __builtin_amdgcn_exp2f(s[r]), dens[r]);
        b1 = nb1; p0 = np0;
    }

    // ---- reduce over the 32 n-lanes (cols), plain store (no atomics)
    #pragma unroll
    for (int r = 0; r < 16; r++) {
        float v = dens[r];
        v += __shfl_xor(v, 1, 64);
        v += __shfl_xor(v, 2, 64);
        v += __shfl_xor(v, 4, 64);
        v += __shfl_xor(v, 8, 64);
        v += __shfl_xor(v, 16, 64);
        if (col32 == 0) {
            int q = qg * 32 + (r & 3) + 8 * (r >> 2) + 4 * khalf;
            part[(size_t)chunk * Q + q] = v;
        }
    }
}

// ---------------- finalize: parallel chunk reduce + wave-parallel wsum + log ------
// 32 blocks x 256 threads; each block covers 64 queries, 4 threads per query
// (each summing 32 chunks, coalesced), LDS combine, 64 threads finalize.
__global__ __launch_bounds__(256) void fin_kernel(
        const float* __restrict__ X, const float* __restrict__ part,
        const float* __restrict__ wpart, float* __restrict__ out, int Q) {
    __shared__ float sred[4][FIN_QPB];
    __shared__ float swsum;

    const int tid = threadIdx.x;
    const int qi = tid & (FIN_QPB - 1);
    const int seg = tid >> 6;              // which 32-chunk segment (0..3)
    const int q = blockIdx.x * FIN_QPB + qi;

    // partial sum over this segment's 32 chunks (coalesced across qi lanes)
    float a0 = 0.f, a1 = 0.f, a2 = 0.f, a3 = 0.f;
    const int c0 = seg * 32;
    #pragma unroll 4
    for (int c = 0; c < 32; c += 4) {
        a0 += part[(size_t)(c0 + c + 0) * Q + q];
        a1 += part[(size_t)(c0 + c + 1) * Q + q];
        a2 += part[(size_t)(c0 + c + 2) * Q + q];
        a3 += part[(size_t)(c0 + c + 3) * Q + q];
    }
    sred[seg][qi] = (a0 + a1) + (a2 + a3);

    // wave 0: wsum via 2 loads/lane + shuffle reduce (128 chunks)
    if (tid < 64) {
        float wv = wpart[tid] + wpart[tid + 64];
        #pragma unroll
        for (int off = 32; off > 0; off >>= 1) wv += __shfl_down(wv, off, 64);
        if (tid == 0) swsum = wv;
    }
    __syncthreads();

    if (tid < FIN_QPB) {
        float dsum = (sred[0][tid] + sred[1][tid]) + (sred[2][tid] + sred[3][tid]);
        int qq = blockIdx.x * FIN_QPB + tid;
        const float4* xp = (const float4*)(X + (size_t)qq * D);
        float4 x0 = xp[0], x1 = xp[1], x2 = xp[2], x3 = xp[3];
        float xx = x0.x*x0.x + x0.y*x0.y + x0.z*x0.z + x0.w*x0.w
                 + x1.x*x1.x + x1.y*x1.y + x1.z*x1.z + x1.w*x1.w
                 + x2.x*x2.x + x2.y*x2.y + x2.z*x2.z + x2.w*x2.w
                 + x3.x*x3.x + x3.y*x3.y + x3.z*x3.z + x3.w*x3.w;
        float aq = -0.5f * LOG2E * xx;
        const float ln_norm = -8.f * 1.8378770664093453f;  // ln((2*pi)^-8)
        out[qq] = LN2 * (aq + __builtin_amdgcn_logf(dsum)
                            - __builtin_amdgcn_logf(swsum)) + ln_norm;
    }
}

extern "C" void kernel_launch(void* const* d_in, const int* in_sizes, int n_in,
                              void* d_out, int out_size, void* d_ws, size_t ws_size,
                              hipStream_t stream) {
    const float* X    = (const float*)d_in[0];
    const float* data = (const float*)d_in[1];
    const float* w    = (const float*)d_in[2];
    float* out = (float*)d_out;
    int Q = in_sizes[0] / D;   // 2048
    int N = in_sizes[1] / D;   // 100000

    // ws layout (floats): [0..NCH) wpart, then part (NCH*Q floats).
    // Everything written before read each launch -> no memset needed.
    float* wpart = (float*)d_ws;
    float* part  = wpart + NCH;

    dim3 grid(Q / (4 * 32), NCH);   // (16, 128)
    dens_kernel<<<grid, 256, 0, stream>>>(X, data, w, part, wpart, Q, N);

    fin_kernel<<<Q / FIN_QPB, 256, 0, stream>>>(X, part, wpart, out, Q);
}